// Round 14
// baseline (224.027 us; speedup 1.0000x reference)
//
#include <hip/hip_runtime.h>
#include <math.h>

// Shapes fixed by setup_inputs: B=4, N=4096 (=64*64), C=768, h=12, d=64
#define B_SZ   4
#define N_SEQ  4096
#define C_DIM  768
#define NH     12
#define HD     64
#define NBH    (B_SZ*NH)
#define SCALE  0.125f
#define M_ROWS (B_SZ*N_SEQ)

typedef unsigned short u16;
typedef short s16x8 __attribute__((ext_vector_type(8)));   // 8 f16 = 4 VGPRs
typedef float f32x4 __attribute__((ext_vector_type(4)));
typedef u16 u16x8 __attribute__((ext_vector_type(8)));

__device__ __forceinline__ u16 f2h(float f) { _Float16 h = (_Float16)f; return __builtin_bit_cast(u16, h); }  // RTN
__device__ __forceinline__ float h2f(u16 u) { return (float)__builtin_bit_cast(_Float16, u); }

__device__ __forceinline__ s16x8 pack_h8(f32x4 x, f32x4 y) {   // RTN pack
    s16x8 o;
    #pragma unroll
    for (int i = 0; i < 4; ++i) { o[i] = (short)f2h(x[i]); o[i+4] = (short)f2h(y[i]); }
    return o;
}

typedef const __attribute__((address_space(1))) void GLBV;
typedef __attribute__((address_space(3))) void LDSV;
#define GLDS(g, l) __builtin_amdgcn_global_load_lds((GLBV*)(g), (LDSV*)(l), 16, 0, 0)

// ---------------- fp32 -> f16 weight convert ----------------
__global__ __launch_bounds__(256)
void cvt_w(const float* __restrict__ w0, const float* __restrict__ w1,
           const float* __restrict__ w2, const float* __restrict__ w3,
           u16* __restrict__ o0, u16* __restrict__ o1, u16* __restrict__ o2, u16* __restrict__ o3) {
    size_t i = ((size_t)blockIdx.x * 256 + threadIdx.x) * 8;
    const float* srcs[4] = {w0 + i, w1 + i, w2 + i, w3 + i};
    u16* dsts[4] = {o0 + i, o1 + i, o2 + i, o3 + i};
    #pragma unroll
    for (int s = 0; s < 4; ++s) {
        float4 x = *(const float4*)srcs[s];
        float4 y = *(const float4*)(srcs[s] + 4);
        u16x8 o;
        o[0] = f2h(x.x); o[1] = f2h(x.y); o[2] = f2h(x.z); o[3] = f2h(x.w);
        o[4] = f2h(y.x); o[5] = f2h(y.y); o[6] = f2h(y.z); o[7] = f2h(y.w);
        *(u16x8*)dsts[s] = o;
    }
}

// ---------------- rope tables (N_SEQ x 64), fp32 ----------------
__global__ void rope_table_k(const int* __restrict__ dH, const int* __restrict__ dW,
                             float* __restrict__ sin_t, float* __restrict__ cos_t) {
    int idx = blockIdx.x * 256 + threadIdx.x;
    if (idx >= N_SEQ * HD) return;
    int n = idx >> 6, j = idx & 63;
    int Wd = dW[0];
    int hh = n / Wd, ww = n % Wd;
    int jj = j & 31;
    float pos = (j < 32) ? (float)hh : (float)ww;
    float freq = powf(10000.0f, -((float)(jj >> 1) / 15.0f));
    float th = pos * freq;
    sin_t[idx] = sinf(th);
    cos_t[idx] = cosf(th);
}

// ==================== GEMM geometry (round-14) ====================
// 128x128 tile, BK=64, 256 threads = 4 waves (2x2), wave tile 64x64, acc[4][4].
// 32 MFMAs per barrier-pair per wave (2x round-13). Sync skeleton unchanged:
// { barrier; GLDS xN; barrier; compute }. Both-sides XOR swizzle (rule 21).

// ---------------- merged K/V projection: one 1536-block launch ----------------
__global__ __launch_bounds__(256)
void gemm_kv(const float* __restrict__ Ak, const float* __restrict__ Av,
             const u16* __restrict__ Wk16, const u16* __restrict__ Wv16,
             const float* __restrict__ bk, const float* __restrict__ bv,
             u16* __restrict__ Ko, u16* __restrict__ Vo) {
    constexpr int K = C_DIM, Nn = C_DIM;
    __shared__ __align__(16) float As[128 * 64];   // 32KB
    __shared__ __align__(16) u16  Bs[128 * 64];    // 16KB
    const int t = threadIdx.x;
    const int lane = t & 63, w = t >> 6;           // 4 waves
    const int wr = w >> 1, wc = w & 1;             // 2x2 wave grid, wave tile 64x64
    const int sel = (blockIdx.x >= 768);           // 0 = K, 1 = V
    const float* A    = sel ? Av   : Ak;
    const u16*  Bw    = sel ? Wv16 : Wk16;
    const float* bias = sel ? bv   : bk;
    u16* Cc           = sel ? Vo   : Ko;
    const bool act = !sel;
    const int bid = blockIdx.x - (sel ? 768 : 0);
    const int wg = (bid & 7) * 96 + (bid >> 3);    // XCD-chunked, 768%8==0 bijective
    const int bx = wg % 6, by = wg / 6;
    const int m0 = by * 128, n0 = bx * 128;

    const int ra = lane & 15, kgu = lane >> 4;     // frag row / k-group

    // A staging: 8 rounds x 16 rows x 256B; lane -> row w*4+kgu (within round), 16B unit lane&15.
    // Source pre-swizzled on row&7 = ((w&1)*4 + kgu).
    const int arow = w * 4 + kgu;
    const int acolb = ((lane & 15) * 16) ^ ((((w & 1) * 4 + kgu) & 7) << 5);
    const char* gA = (const char*)(A + (size_t)(m0 + arow) * K) + acolb;
    // B staging: 4 rounds x 32 rows x 128B; lane -> row w*8 + (lane>>3), 16B unit lane&7.
    const int brow = w * 8 + (lane >> 3);
    const int bcol = ((lane & 7) * 8) ^ ((lane >> 3) << 3); // u16 units
    const u16* gB = Bw + (size_t)(n0 + brow) * K + bcol;

    f32x4 acc[4][4] = {};

    for (int k0 = 0; k0 < K; k0 += 64) {
        __syncthreads();
        #pragma unroll
        for (int r = 0; r < 8; ++r)
            GLDS(gA + (size_t)r * 16 * K * 4, &As[(r * 16 + w * 4) * 64]);
        #pragma unroll
        for (int r = 0; r < 4; ++r)
            GLDS(gB + (size_t)r * 32 * K, &Bs[(r * 32 + w * 8) * 64]);
        gA += 256; gB += 64;
        __syncthreads();
        #pragma unroll
        for (int kk = 0; kk < 2; ++kk) {
            const int fo = (kk * 32 + kgu * 8) ^ ((ra & 7) << 3);   // element units
            s16x8 av[4], bvv[4];
            #pragma unroll
            for (int i = 0; i < 4; ++i) {
                const float* ap = &As[(wr * 64 + i * 16 + ra) * 64 + fo];
                av[i] = pack_h8(*(const f32x4*)ap, *(const f32x4*)(ap + 4));
            }
            #pragma unroll
            for (int j = 0; j < 4; ++j)
                bvv[j] = *(const s16x8*)&Bs[(wc * 64 + j * 16 + ra) * 64 + fo];
            #pragma unroll
            for (int i = 0; i < 4; ++i)
                #pragma unroll
                for (int j = 0; j < 4; ++j)
                    asm("v_mfma_f32_16x16x32_f16 %0, %1, %2, %0"
                        : "+v"(acc[i][j]) : "v"(av[i]), "v"(bvv[j]));
        }
    }

    const int cr4 = kgu * 4, cc = ra;
    #pragma unroll
    for (int j = 0; j < 4; ++j) {
        const int col = n0 + wc * 64 + j * 16 + cc;
        const float bj = bias[col];
        #pragma unroll
        for (int i = 0; i < 4; ++i) {
            const int row = m0 + wr * 64 + i * 16 + cr4;
            #pragma unroll
            for (int r = 0; r < 4; ++r) {
                float v = acc[i][j][r] + bj;
                if (act) v = (v > 0.f) ? (v + 1.f) : __expf(v);   // elu+1
                Cc[(size_t)(row + r) * Nn + col] = f2h(v);
            }
        }
    }
}

// ---------------- Q-projection: GEMM + elu+1 + fp32 z + fp32 rope -> qr(f16), z(f32) ----------------
__global__ __launch_bounds__(256)
void gemm_q(const float* __restrict__ A, const u16* __restrict__ Bw,
            const float* __restrict__ bias, const float* __restrict__ km,
            const float* __restrict__ sin_t, const float* __restrict__ cos_t,
            u16* __restrict__ Qr, float* __restrict__ zbuf) {
    constexpr int K = C_DIM, Nn = C_DIM;
    __shared__ __align__(16) float As[128 * 64];
    __shared__ __align__(16) u16  Bs[128 * 64];
    const int t = threadIdx.x;
    const int lane = t & 63, w = t >> 6;
    const int wr = w >> 1, wc = w & 1;
    const int bid = blockIdx.x;
    const int wg = (bid & 7) * 96 + (bid >> 3);
    const int bx = wg % 6, by = wg / 6;
    const int m0 = by * 128, n0 = bx * 128;

    const int ra = lane & 15, kgu = lane >> 4;

    const int arow = w * 4 + kgu;
    const int acolb = ((lane & 15) * 16) ^ ((((w & 1) * 4 + kgu) & 7) << 5);
    const char* gA = (const char*)(A + (size_t)(m0 + arow) * K) + acolb;
    const int brow = w * 8 + (lane >> 3);
    const int bcol = ((lane & 7) * 8) ^ ((lane >> 3) << 3);
    const u16* gB = Bw + (size_t)(n0 + brow) * K + bcol;

    f32x4 acc[4][4] = {};

    for (int k0 = 0; k0 < K; k0 += 64) {
        __syncthreads();
        #pragma unroll
        for (int r = 0; r < 8; ++r)
            GLDS(gA + (size_t)r * 16 * K * 4, &As[(r * 16 + w * 4) * 64]);
        #pragma unroll
        for (int r = 0; r < 4; ++r)
            GLDS(gB + (size_t)r * 32 * K, &Bs[(r * 32 + w * 8) * 64]);
        gA += 256; gB += 64;
        __syncthreads();
        #pragma unroll
        for (int kk = 0; kk < 2; ++kk) {
            const int fo = (kk * 32 + kgu * 8) ^ ((ra & 7) << 3);
            s16x8 av[4], bvv[4];
            #pragma unroll
            for (int i = 0; i < 4; ++i) {
                const float* ap = &As[(wr * 64 + i * 16 + ra) * 64 + fo];
                av[i] = pack_h8(*(const f32x4*)ap, *(const f32x4*)(ap + 4));
            }
            #pragma unroll
            for (int j = 0; j < 4; ++j)
                bvv[j] = *(const s16x8*)&Bs[(wc * 64 + j * 16 + ra) * 64 + fo];
            #pragma unroll
            for (int i = 0; i < 4; ++i)
                #pragma unroll
                for (int j = 0; j < 4; ++j)
                    asm("v_mfma_f32_16x16x32_f16 %0, %1, %2, %0"
                        : "+v"(acc[i][j]) : "v"(av[i]), "v"(bvv[j]));
        }
    }

    // epilogue: elu+1 (fp32), z = scale * q . km (exact, 16-lane reduce), rope (fp32), store f16
    const int cr4 = kgu * 4, cc = ra;
    const int b = m0 >> 12;                       // batch (128 | 4096, no straddle)
    const int h = (n0 >> 6) + wc;                 // head owned by this wave (64-col span)
    float kmv[4];
    #pragma unroll
    for (int j = 0; j < 4; ++j) kmv[j] = km[(b * NH + h) * HD + j * 16 + cc];

    #pragma unroll
    for (int i = 0; i < 4; ++i) {
        #pragma unroll
        for (int r = 0; r < 4; ++r) {
            const int row = m0 + wr * 64 + i * 16 + cr4 + r;   // global row
            const int n = row & (N_SEQ - 1);
            float q[4], zp = 0.f;
            #pragma unroll
            for (int j = 0; j < 4; ++j) {
                float v = acc[i][j][r] + bias[n0 + wc * 64 + j * 16 + cc];
                v = (v > 0.f) ? (v + 1.f) : __expf(v);          // elu+1
                q[j] = v;
                zp += v * kmv[j];
            }
            zp += __shfl_xor(zp, 1); zp += __shfl_xor(zp, 2);
            zp += __shfl_xor(zp, 4); zp += __shfl_xor(zp, 8);
            if (cc == 0) zbuf[((size_t)(b * NH + h)) * N_SEQ + n] = zp * SCALE;
            #pragma unroll
            for (int j = 0; j < 4; ++j) {
                const int d = j * 16 + cc;
                const float p = __shfl_xor(q[j], 1);
                const float rot = (d & 1) ? p : -p;
                const size_t toff = (size_t)n * HD + d;
                const float qr = q[j] * cos_t[toff] + rot * sin_t[toff];
                Qr[(size_t)row * Nn + n0 + wc * 64 + d] = f2h(qr);
            }
        }
    }
}

// ---------------- f16-A MFMA GEMM (O-projection): fp32 out ----------------
__global__ __launch_bounds__(256)
void gemm_f16a(const u16* __restrict__ A, const u16* __restrict__ Bw,
               const float* __restrict__ bias, float* __restrict__ Cc) {
    constexpr int K = C_DIM, Nn = C_DIM;
    __shared__ __align__(16) u16 As[128 * 64];   // 16KB
    __shared__ __align__(16) u16 Bs[128 * 64];   // 16KB
    const int t = threadIdx.x;
    const int lane = t & 63, w = t >> 6;
    const int wr = w >> 1, wc = w & 1;
    const int bid = blockIdx.x;
    const int wg = (bid & 7) * 96 + (bid >> 3);
    const int bx = wg % 6, by = wg / 6;
    const int m0 = by * 128, n0 = bx * 128;

    const int ra = lane & 15, kgu = lane >> 4;

    // both operands f16: 4 rounds x 32 rows x 128B each
    const int row0 = w * 8 + (lane >> 3);
    const int col0 = ((lane & 7) * 8) ^ ((lane >> 3) << 3);   // u16 units
    const u16* gA = A + (size_t)(m0 + row0) * K + col0;
    const u16* gB = Bw + (size_t)(n0 + row0) * K + col0;

    f32x4 acc[4][4] = {};

    for (int k0 = 0; k0 < K; k0 += 64) {
        __syncthreads();
        #pragma unroll
        for (int r = 0; r < 4; ++r) {
            GLDS(gA + (size_t)r * 32 * K, &As[(r * 32 + w * 8) * 64]);
            GLDS(gB + (size_t)r * 32 * K, &Bs[(r * 32 + w * 8) * 64]);
        }
        gA += 64; gB += 64;
        __syncthreads();
        #pragma unroll
        for (int kk = 0; kk < 2; ++kk) {
            const int fo = (kk * 32 + kgu * 8) ^ ((ra & 7) << 3);
            s16x8 av[4], bvv[4];
            #pragma unroll
            for (int i = 0; i < 4; ++i)
                av[i] = *(const s16x8*)&As[(wr * 64 + i * 16 + ra) * 64 + fo];
            #pragma unroll
            for (int j = 0; j < 4; ++j)
                bvv[j] = *(const s16x8*)&Bs[(wc * 64 + j * 16 + ra) * 64 + fo];
            #pragma unroll
            for (int i = 0; i < 4; ++i)
                #pragma unroll
                for (int j = 0; j < 4; ++j)
                    asm("v_mfma_f32_16x16x32_f16 %0, %1, %2, %0"
                        : "+v"(acc[i][j]) : "v"(av[i]), "v"(bvv[j]));
        }
    }

    const int cr4 = kgu * 4, cc = ra;
    #pragma unroll
    for (int j = 0; j < 4; ++j) {
        const int col = n0 + wc * 64 + j * 16 + cc;
        const float bj = bias[col];
        #pragma unroll
        for (int i = 0; i < 4; ++i) {
            const int row = m0 + wr * 64 + i * 16 + cr4;
            #pragma unroll
            for (int r = 0; r < 4; ++r)
                Cc[(size_t)(row + r) * Nn + col] = acc[i][j][r] + bj;
        }
    }
}

// ---------------- kv partials + column sums (fused), f16 in ----------------
__global__ __launch_bounds__(256)
void kv_partial(const u16* __restrict__ Kb, const u16* __restrict__ Vb,
                const float* __restrict__ sin_t, const float* __restrict__ cos_t,
                float* __restrict__ pkv, float* __restrict__ pk, float* __restrict__ pv) {
    int bh = blockIdx.x, chunk = blockIdx.y;
    int b = bh / NH, h = bh % NH;
    int t = threadIdx.x, tx = t & 15, ty = t >> 4;
    __shared__ float Kt[32][64];
    __shared__ float Vt[32][64];
    float acc[4][4] = {};
    float sk[8] = {}, sv[8] = {};
    int n0 = chunk * 128;
    int lr = t >> 3, lc = (t & 7) * 8;
    for (int nc = 0; nc < 128; nc += 32) {
        int n = n0 + nc + lr;
        size_t off = ((size_t)b * N_SEQ + n) * C_DIM + h * HD + lc;
        size_t toff = (size_t)n * HD + lc;
        u16x8 k8 = *(const u16x8*)&Kb[off];
        u16x8 v8 = *(const u16x8*)&Vb[off];
        float kf[8], vf[8];
        #pragma unroll
        for (int i = 0; i < 8; ++i) {
            kf[i] = h2f(k8[i]); vf[i] = h2f(v8[i]);
            sk[i] += kf[i]; sv[i] += vf[i];
        }
        float4 s1 = *(const float4*)&sin_t[toff];
        float4 s2 = *(const float4*)&sin_t[toff + 4];
        float4 c1 = *(const float4*)&cos_t[toff];
        float4 c2 = *(const float4*)&cos_t[toff + 4];
        float sn[8] = {s1.x, s1.y, s1.z, s1.w, s2.x, s2.y, s2.z, s2.w};
        float cs[8] = {c1.x, c1.y, c1.z, c1.w, c2.x, c2.y, c2.z, c2.w};
        float kr[8];
        #pragma unroll
        for (int e = 0; e < 8; e += 2) {
            kr[e]   = kf[e] * cs[e]     - kf[e+1] * sn[e];
            kr[e+1] = kf[e+1] * cs[e+1] + kf[e]   * sn[e+1];
        }
        __syncthreads();
        #pragma unroll
        for (int i = 0; i < 8; ++i) { Kt[lr][lc + i] = kr[i]; Vt[lr][lc + i] = vf[i]; }
        __syncthreads();
        #pragma unroll
        for (int nn = 0; nn < 32; ++nn) {
            float a[4], bb[4];
            #pragma unroll
            for (int i = 0; i < 4; ++i) a[i] = Kt[nn][ty * 4 + i];
            #pragma unroll
            for (int j = 0; j < 4; ++j) bb[j] = Vt[nn][tx * 4 + j];
            #pragma unroll
            for (int i = 0; i < 4; ++i)
                #pragma unroll
                for (int j = 0; j < 4; ++j)
                    acc[i][j] += a[i] * bb[j];
        }
    }
    size_t obase = ((size_t)bh * 32 + chunk) * 4096;
    #pragma unroll
    for (int i = 0; i < 4; ++i)
        #pragma unroll
        for (int j = 0; j < 4; ++j)
            pkv[obase + (ty * 4 + i) * 64 + (tx * 4 + j)] = acc[i][j];
    __syncthreads();
    #pragma unroll
    for (int i = 0; i < 8; ++i) { Kt[lr][lc + i] = sk[i]; Vt[lr][lc + i] = sv[i]; }
    __syncthreads();
    if (t < 64) {
        float s1 = 0.f, s2 = 0.f;
        #pragma unroll
        for (int r = 0; r < 32; ++r) { s1 += Kt[r][t]; s2 += Vt[r][t]; }
        pk[((size_t)bh * 32 + chunk) * 64 + t] = s1;
        pv[((size_t)bh * 32 + chunk) * 64 + t] = s2;
    }
}

// ---------------- merged reduce: kvT (f16 hi/lo, transposed [e][d]) + km/vm ----------------
__global__ __launch_bounds__(256)
void kvred(const float* __restrict__ pkv, const float* __restrict__ pk, const float* __restrict__ pv,
           u16* __restrict__ kvT, float* __restrict__ km, float* __restrict__ vm) {
    int bh = blockIdx.x, t = threadIdx.x;
    int u = blockIdx.y * 256 + t;
    float s = 0.f;
    for (int c = 0; c < 32; ++c) s += pkv[((size_t)bh * 32 + c) * 4096 + u];
    s *= (SCALE / N_SEQ);
    int d = u >> 6, e = u & 63;
    u16 hi = f2h(s);
    u16 lo = f2h(s - h2f(hi));
    kvT[(size_t)bh * 8192 + e * 64 + d] = hi;
    kvT[(size_t)bh * 8192 + 4096 + e * 64 + d] = lo;
    if (blockIdx.y == 0 && t < 128) {
        int which = t >> 6, lane = t & 63;
        const float* src = which ? pv : pk;
        float s2 = 0.f;
        for (int c = 0; c < 32; ++c) s2 += src[((size_t)bh * 32 + c) * 64 + lane];
        (which ? vm : km)[bh * 64 + lane] = s2 * (1.0f / N_SEQ);
    }
}

// ---------------- res: MFMA(qr @ kv_hi + qr @ kv_lo) + rescale; in-place on Qr ----------------
#define LDQ 72
__global__ __launch_bounds__(256)
void res_mfma(u16* __restrict__ Qr,
              const u16* __restrict__ kvT,
              const float* __restrict__ vmean, const float* __restrict__ zbuf) {
    __shared__ __align__(16) u16 qs[128 * LDQ];
    __shared__ __align__(16) u16 kvs[2][64 * LDQ];
    __shared__ float zs[128];
    __shared__ float vms[64];
    const int bh = blockIdx.x;
    const int b = bh / NH, h = bh % NH;
    const int n0 = blockIdx.y * 128;
    const int t = threadIdx.x;
    const int lane = t & 63, w = t >> 6;

    {   // stage kv^T hi/lo
        const int r = t >> 2, c = (t & 3) * 16;
        #pragma unroll
        for (int p = 0; p < 2; ++p) {
            size_t g = (size_t)bh * 8192 + p * 4096 + r * 64 + c;
            *(u16x8*)&kvs[p][r * LDQ + c]     = *(const u16x8*)&kvT[g];
            *(u16x8*)&kvs[p][r * LDQ + c + 8] = *(const u16x8*)&kvT[g + 8];
        }
    }
    if (t < 64) vms[t] = vmean[bh * 64 + t];
    else if (t < 192) zs[t - 64] = zbuf[(size_t)bh * N_SEQ + n0 + (t - 64)];
    // stage qr
    #pragma unroll
    for (int ri = 0; ri < 4; ++ri) {
        const int row = ri * 32 + (t >> 3);
        const int c = (t & 7) * 8;
        size_t off = ((size_t)b * N_SEQ + n0 + row) * C_DIM + (size_t)h * HD + c;
        *(u16x8*)&qs[row * LDQ + c] = *(const u16x8*)&Qr[off];
    }
    __syncthreads();

    f32x4 acc[2][4] = {};
    const int ra = lane & 15, kg = (lane >> 4) * 8;
    #pragma unroll
    for (int p = 0; p < 2; ++p) {
        #pragma unroll
        for (int hh = 0; hh < 2; ++hh) {
            s16x8 bv4[4];
            #pragma unroll
            for (int j = 0; j < 4; ++j)
                bv4[j] = *(const s16x8*)&kvs[p][(j * 16 + ra) * LDQ + hh * 32 + kg];
            #pragma unroll
            for (int i = 0; i < 2; ++i) {
                s16x8 av = *(const s16x8*)&qs[(w * 32 + i * 16 + ra) * LDQ + hh * 32 + kg];
                #pragma unroll
                for (int j = 0; j < 4; ++j)
                    asm("v_mfma_f32_16x16x32_f16 %0, %1, %2, %0"
                        : "+v"(acc[i][j]) : "v"(av), "v"(bv4[j]));
            }
        }
    }

    const int cr4 = (lane >> 4) * 4, cc = lane & 15;
    #pragma unroll
    for (int i = 0; i < 2; ++i) {
        #pragma unroll
        for (int j = 0; j < 4; ++j) {
            const int col = j * 16 + cc;
            const float vmc = vms[col];
            #pragma unroll
            for (int r = 0; r < 4; ++r) {
                const int row = w * 32 + i * 16 + cr4 + r;
                const float z = zs[row];
                const float v = acc[i][j][r] * (1.0f + 1.0f / (z + 1e-6f)) - z * vmc;
                Qr[((size_t)b * N_SEQ + n0 + row) * C_DIM + (size_t)h * HD + col] = f2h(v);
            }
        }
    }
}

extern "C" void kernel_launch(void* const* d_in, const int* in_sizes, int n_in,
                              void* d_out, int out_size, void* d_ws, size_t ws_size,
                              hipStream_t stream) {
    const float* query = (const float*)d_in[0];
    const float* key   = (const float*)d_in[1];
    const float* value = (const float*)d_in[2];
    const float* Wq = (const float*)d_in[3];
    const float* bq = (const float*)d_in[4];
    const float* Wk = (const float*)d_in[5];
    const float* bk = (const float*)d_in[6];
    const float* Wv = (const float*)d_in[7];
    const float* bv = (const float*)d_in[8];
    const float* Wo = (const float*)d_in[9];
    const float* bo = (const float*)d_in[10];
    const int* dH = (const int*)d_in[11];
    const int* dW = (const int*)d_in[12];
    float* out = (float*)d_out;

    const size_t mc = (size_t)M_ROWS * C_DIM;   // 12,582,912
    const size_t wsz = (size_t)C_DIM * C_DIM;   // 589,824

    // f16 buffers
    u16* ws16 = (u16*)d_ws;
    u16* Qr  = ws16;             // mc (qr, then res in-place)
    u16* Kb  = Qr + mc;          // mc
    u16* Vb  = Kb + mc;          // mc
    u16* wqb = Vb + mc;          // wsz x4
    u16* wkb = wqb + wsz;
    u16* wvb = wkb + wsz;
    u16* wob = wvb + wsz;
    u16* kvT = wob + wsz;        // NBH*8192 (hi/lo)

    // fp32 buffers
    float* wsf = (float*)(kvT + (size_t)NBH * 8192);
    float* sin_t = wsf;                          // 262144
    float* cos_t = sin_t + (size_t)N_SEQ * HD;   // 262144
    float* pk    = cos_t + (size_t)N_SEQ * HD;   // NBH*32*64
    float* pv    = pk + (size_t)NBH * 32 * 64;
    float* km    = pv + (size_t)NBH * 32 * 64;   // NBH*64
    float* vm    = km + NBH * 64;
    float* zbuf  = vm + NBH * 64;                // NBH*4096
    float* pkv   = zbuf + (size_t)NBH * N_SEQ;   // NBH*32*4096 = 25MB

    // weights + tables
    cvt_w<<<dim3(288), dim3(256), 0, stream>>>(Wq, Wk, Wv, Wo, wqb, wkb, wvb, wob);
    rope_table_k<<<dim3(1024), dim3(256), 0, stream>>>(dH, dW, sin_t, cos_t);

    // K + V projections in ONE 1536-block launch (disjoint halves)
    gemm_kv<<<dim3(1536), dim3(256), 0, stream>>>(key, value, wkb, wvb, bk, bv, Kb, Vb);

    // kv partials (+ fused column sums), then merged reduce -> km, vm, kvT
    kv_partial<<<dim3(NBH, 32), dim3(256), 0, stream>>>(Kb, Vb, sin_t, cos_t, pkv, pk, pv);
    kvred<<<dim3(NBH, 16), dim3(256), 0, stream>>>(pkv, pk, pv, kvT, km, vm);

    // Q projection with fused exact-z + rope
    gemm_q<<<dim3(768), dim3(256), 0, stream>>>(query, wqb, bq, km, sin_t, cos_t, Qr, zbuf);

    // res (in-place on Qr)
    res_mfma<<<dim3(NBH, N_SEQ / 128), dim3(256), 0, stream>>>(Qr, kvT, vm, zbuf);

    // output projection (fp32 out)
    gemm_f16a<<<dim3(768), dim3(256), 0, stream>>>(Qr, wob, bo, out);
}

// Round 16
// 207.234 us; speedup vs baseline: 1.0810x; 1.0810x over previous
//
#include <hip/hip_runtime.h>
#include <math.h>

// Shapes fixed by setup_inputs: B=4, N=4096 (=64*64), C=768, h=12, d=64
#define B_SZ   4
#define N_SEQ  4096
#define C_DIM  768
#define NH     12
#define HD     64
#define NBH    (B_SZ*NH)
#define SCALE  0.125f
#define M_ROWS (B_SZ*N_SEQ)

typedef unsigned short u16;
typedef short s16x8 __attribute__((ext_vector_type(8)));   // 8 f16 = 4 VGPRs
typedef float f32x4 __attribute__((ext_vector_type(4)));
typedef u16 u16x8 __attribute__((ext_vector_type(8)));

__device__ __forceinline__ u16 f2h(float f) { _Float16 h = (_Float16)f; return __builtin_bit_cast(u16, h); }  // RTN
__device__ __forceinline__ float h2f(u16 u) { return (float)__builtin_bit_cast(_Float16, u); }

__device__ __forceinline__ s16x8 pack_h8(f32x4 x, f32x4 y) {   // RTN pack
    s16x8 o;
    #pragma unroll
    for (int i = 0; i < 4; ++i) { o[i] = (short)f2h(x[i]); o[i+4] = (short)f2h(y[i]); }
    return o;
}

typedef const __attribute__((address_space(1))) void GLBV;
typedef __attribute__((address_space(3))) void LDSV;
#define GLDS(g, l) __builtin_amdgcn_global_load_lds((GLBV*)(g), (LDSV*)(l), 16, 0, 0)

// ---------------- merged prep: weight cvt (bid<288) + rope tables (bid>=288) ----------------
__global__ __launch_bounds__(256)
void prep(const float* __restrict__ w0, const float* __restrict__ w1,
          const float* __restrict__ w2, const float* __restrict__ w3,
          u16* __restrict__ o0, u16* __restrict__ o1, u16* __restrict__ o2, u16* __restrict__ o3,
          const int* __restrict__ dW,
          float* __restrict__ sin_t, float* __restrict__ cos_t) {
    if (blockIdx.x < 288) {
        size_t i = ((size_t)blockIdx.x * 256 + threadIdx.x) * 8;
        const float* srcs[4] = {w0 + i, w1 + i, w2 + i, w3 + i};
        u16* dsts[4] = {o0 + i, o1 + i, o2 + i, o3 + i};
        #pragma unroll
        for (int s = 0; s < 4; ++s) {
            float4 x = *(const float4*)srcs[s];
            float4 y = *(const float4*)(srcs[s] + 4);
            u16x8 o;
            o[0] = f2h(x.x); o[1] = f2h(x.y); o[2] = f2h(x.z); o[3] = f2h(x.w);
            o[4] = f2h(y.x); o[5] = f2h(y.y); o[6] = f2h(y.z); o[7] = f2h(y.w);
            *(u16x8*)dsts[s] = o;
        }
    } else {
        int idx = (blockIdx.x - 288) * 256 + threadIdx.x;
        if (idx >= N_SEQ * HD) return;
        int n = idx >> 6, j = idx & 63;
        int Wd = dW[0];
        int hh = n / Wd, ww = n % Wd;
        int jj = j & 31;
        float pos = (j < 32) ? (float)hh : (float)ww;
        float freq = powf(10000.0f, -((float)(jj >> 1) / 15.0f));
        float th = pos * freq;
        sin_t[idx] = sinf(th);
        cos_t[idx] = cosf(th);
    }
}

// ==================== GEMM geometry (round-13 verified) ====================
// 128x128 tile, BK=64, 512 threads = 8 waves (4 row x 2 col), wave tile 32x64.
// 12 K-steps. Sync skeleton: { barrier; GLDS xN; barrier; compute }.

// ---------------- merged K/V projection: one 1536-block launch ----------------
// bid < 768 -> K-proj (elu+1); bid >= 768 -> V-proj (no act). Halves are fully disjoint.
__global__ __launch_bounds__(512)
void gemm_kv(const float* __restrict__ Ak, const float* __restrict__ Av,
             const u16* __restrict__ Wk16, const u16* __restrict__ Wv16,
             const float* __restrict__ bk, const float* __restrict__ bv,
             u16* __restrict__ Ko, u16* __restrict__ Vo) {
    constexpr int K = C_DIM, Nn = C_DIM;
    __shared__ __align__(16) float As[128 * 64];   // 32KB
    __shared__ __align__(16) u16  Bs[128 * 64];    // 16KB
    const int t = threadIdx.x;
    const int lane = t & 63, w = t >> 6;           // 8 waves
    const int wr = w >> 1, wc = w & 1;             // 4x2 wave grid, wave tile 32x64
    const int sel = (blockIdx.x >= 768);           // 0 = K, 1 = V
    const float* A    = sel ? Av   : Ak;
    const u16*  Bw    = sel ? Wv16 : Wk16;
    const float* bias = sel ? bv   : bk;
    u16* Cc           = sel ? Vo   : Ko;
    const bool act = !sel;
    const int bid = blockIdx.x - (sel ? 768 : 0);
    const int wg = (bid & 7) * 96 + (bid >> 3);    // XCD-chunked, 768%8==0 bijective
    const int bx = wg % 6, by = wg / 6;
    const int m0 = by * 128, n0 = bx * 128;

    const int ra = lane & 15, kgu = lane >> 4;     // frag row / k-group

    // A staging: 4 rounds x 32 rows x 256B; source pre-swizzled (rule 21)
    const int arow = w * 4 + kgu;                           // row within round (0..31)
    const int acolb = ((lane & 15) * 16) ^ ((((w & 1) * 4 + kgu) & 7) << 5);
    const char* gA = (const char*)(A + (size_t)(m0 + arow) * K) + acolb;
    // B staging: 2 rounds x 64 rows x 128B; source pre-swizzled
    const int brow = w * 8 + (lane >> 3);                   // row within round (0..63)
    const int bcol = ((lane & 7) * 8) ^ ((lane >> 3) << 3); // u16 units
    const u16* gB = Bw + (size_t)(n0 + brow) * K + bcol;

    f32x4 acc[2][4] = {};

    for (int k0 = 0; k0 < K; k0 += 64) {
        __syncthreads();
        GLDS(gA,                          &As[(0 * 32 + w * 4) * 64]);
        GLDS(gA + (size_t)32 * K * 4,     &As[(1 * 32 + w * 4) * 64]);
        GLDS(gA + (size_t)64 * K * 4,     &As[(2 * 32 + w * 4) * 64]);
        GLDS(gA + (size_t)96 * K * 4,     &As[(3 * 32 + w * 4) * 64]);
        GLDS(gB,                          &Bs[(0 * 64 + w * 8) * 64]);
        GLDS(gB + (size_t)64 * K,         &Bs[(1 * 64 + w * 8) * 64]);
        gA += 256; gB += 64;
        __syncthreads();
        #pragma unroll
        for (int kk = 0; kk < 2; ++kk) {
            const int fo = (kk * 32 + kgu * 8) ^ ((ra & 7) << 3);   // element units
            s16x8 av[2], bvv[4];
            #pragma unroll
            for (int i = 0; i < 2; ++i) {
                const float* ap = &As[(wr * 32 + i * 16 + ra) * 64 + fo];
                av[i] = pack_h8(*(const f32x4*)ap, *(const f32x4*)(ap + 4));
            }
            #pragma unroll
            for (int j = 0; j < 4; ++j)
                bvv[j] = *(const s16x8*)&Bs[(wc * 64 + j * 16 + ra) * 64 + fo];
            #pragma unroll
            for (int i = 0; i < 2; ++i)
                #pragma unroll
                for (int j = 0; j < 4; ++j)
                    asm("v_mfma_f32_16x16x32_f16 %0, %1, %2, %0"
                        : "+v"(acc[i][j]) : "v"(av[i]), "v"(bvv[j]));
        }
    }

    const int cr4 = kgu * 4, cc = ra;
    #pragma unroll
    for (int j = 0; j < 4; ++j) {
        const int col = n0 + wc * 64 + j * 16 + cc;
        const float bj = bias[col];
        #pragma unroll
        for (int i = 0; i < 2; ++i) {
            const int row = m0 + wr * 32 + i * 16 + cr4;
            #pragma unroll
            for (int r = 0; r < 4; ++r) {
                float v = acc[i][j][r] + bj;
                if (act) v = (v > 0.f) ? (v + 1.f) : __expf(v);   // elu+1
                Cc[(size_t)(row + r) * Nn + col] = f2h(v);
            }
        }
    }
}

// ---------------- Q-projection: GEMM + elu+1 + fp32 z + fp32 rope -> qr(f16), z(f32) ----------------
__global__ __launch_bounds__(512)
void gemm_q(const float* __restrict__ A, const u16* __restrict__ Bw,
            const float* __restrict__ bias, const float* __restrict__ km,
            const float* __restrict__ sin_t, const float* __restrict__ cos_t,
            u16* __restrict__ Qr, float* __restrict__ zbuf) {
    constexpr int K = C_DIM, Nn = C_DIM;
    __shared__ __align__(16) float As[128 * 64];
    __shared__ __align__(16) u16  Bs[128 * 64];
    const int t = threadIdx.x;
    const int lane = t & 63, w = t >> 6;
    const int wr = w >> 1, wc = w & 1;
    const int bid = blockIdx.x;
    const int wg = (bid & 7) * 96 + (bid >> 3);
    const int bx = wg % 6, by = wg / 6;
    const int m0 = by * 128, n0 = bx * 128;

    const int ra = lane & 15, kgu = lane >> 4;

    const int arow = w * 4 + kgu;
    const int acolb = ((lane & 15) * 16) ^ ((((w & 1) * 4 + kgu) & 7) << 5);
    const char* gA = (const char*)(A + (size_t)(m0 + arow) * K) + acolb;
    const int brow = w * 8 + (lane >> 3);
    const int bcol = ((lane & 7) * 8) ^ ((lane >> 3) << 3);
    const u16* gB = Bw + (size_t)(n0 + brow) * K + bcol;

    f32x4 acc[2][4] = {};

    for (int k0 = 0; k0 < K; k0 += 64) {
        __syncthreads();
        GLDS(gA,                          &As[(0 * 32 + w * 4) * 64]);
        GLDS(gA + (size_t)32 * K * 4,     &As[(1 * 32 + w * 4) * 64]);
        GLDS(gA + (size_t)64 * K * 4,     &As[(2 * 32 + w * 4) * 64]);
        GLDS(gA + (size_t)96 * K * 4,     &As[(3 * 32 + w * 4) * 64]);
        GLDS(gB,                          &Bs[(0 * 64 + w * 8) * 64]);
        GLDS(gB + (size_t)64 * K,         &Bs[(1 * 64 + w * 8) * 64]);
        gA += 256; gB += 64;
        __syncthreads();
        #pragma unroll
        for (int kk = 0; kk < 2; ++kk) {
            const int fo = (kk * 32 + kgu * 8) ^ ((ra & 7) << 3);
            s16x8 av[2], bvv[4];
            #pragma unroll
            for (int i = 0; i < 2; ++i) {
                const float* ap = &As[(wr * 32 + i * 16 + ra) * 64 + fo];
                av[i] = pack_h8(*(const f32x4*)ap, *(const f32x4*)(ap + 4));
            }
            #pragma unroll
            for (int j = 0; j < 4; ++j)
                bvv[j] = *(const s16x8*)&Bs[(wc * 64 + j * 16 + ra) * 64 + fo];
            #pragma unroll
            for (int i = 0; i < 2; ++i)
                #pragma unroll
                for (int j = 0; j < 4; ++j)
                    asm("v_mfma_f32_16x16x32_f16 %0, %1, %2, %0"
                        : "+v"(acc[i][j]) : "v"(av[i]), "v"(bvv[j]));
        }
    }

    // epilogue: elu+1 (fp32), z = scale * q . km (exact, 16-lane reduce), rope (fp32), store f16
    const int cr4 = kgu * 4, cc = ra;
    const int b = m0 >> 12;                       // batch (128 | 4096, no straddle)
    const int h = (n0 >> 6) + wc;                 // head owned by this wave
    float kmv[4];
    #pragma unroll
    for (int j = 0; j < 4; ++j) kmv[j] = km[(b * NH + h) * HD + j * 16 + cc];

    #pragma unroll
    for (int i = 0; i < 2; ++i) {
        #pragma unroll
        for (int r = 0; r < 4; ++r) {
            const int row = m0 + wr * 32 + i * 16 + cr4 + r;   // global row
            const int n = row & (N_SEQ - 1);
            float q[4], zp = 0.f;
            #pragma unroll
            for (int j = 0; j < 4; ++j) {
                float v = acc[i][j][r] + bias[n0 + wc * 64 + j * 16 + cc];
                v = (v > 0.f) ? (v + 1.f) : __expf(v);          // elu+1
                q[j] = v;
                zp += v * kmv[j];
            }
            zp += __shfl_xor(zp, 1); zp += __shfl_xor(zp, 2);
            zp += __shfl_xor(zp, 4); zp += __shfl_xor(zp, 8);
            if (cc == 0) zbuf[((size_t)(b * NH + h)) * N_SEQ + n] = zp * SCALE;
            #pragma unroll
            for (int j = 0; j < 4; ++j) {
                const int d = j * 16 + cc;
                const float p = __shfl_xor(q[j], 1);
                const float rot = (d & 1) ? p : -p;
                const size_t toff = (size_t)n * HD + d;
                const float qr = q[j] * cos_t[toff] + rot * sin_t[toff];
                Qr[(size_t)row * Nn + n0 + wc * 64 + d] = f2h(qr);
            }
        }
    }
}

// ---------------- f16-A MFMA GEMM (O-projection): fp32 out ----------------
__global__ __launch_bounds__(512)
void gemm_f16a(const u16* __restrict__ A, const u16* __restrict__ Bw,
               const float* __restrict__ bias, float* __restrict__ Cc) {
    constexpr int K = C_DIM, Nn = C_DIM;
    __shared__ __align__(16) u16 As[128 * 64];   // 16KB
    __shared__ __align__(16) u16 Bs[128 * 64];   // 16KB
    const int t = threadIdx.x;
    const int lane = t & 63, w = t >> 6;
    const int wr = w >> 1, wc = w & 1;
    const int bid = blockIdx.x;
    const int wg = (bid & 7) * 96 + (bid >> 3);
    const int bx = wg % 6, by = wg / 6;
    const int m0 = by * 128, n0 = bx * 128;

    const int ra = lane & 15, kgu = lane >> 4;

    // both operands f16: 2 rounds x 64 rows x 128B each
    const int row0 = w * 8 + (lane >> 3);
    const int col0 = ((lane & 7) * 8) ^ ((lane >> 3) << 3);   // u16 units
    const u16* gA = A + (size_t)(m0 + row0) * K + col0;
    const u16* gB = Bw + (size_t)(n0 + row0) * K + col0;

    f32x4 acc[2][4] = {};

    for (int k0 = 0; k0 < K; k0 += 64) {
        __syncthreads();
        GLDS(gA,                      &As[(0 * 64 + w * 8) * 64]);
        GLDS(gA + (size_t)64 * K,     &As[(1 * 64 + w * 8) * 64]);
        GLDS(gB,                      &Bs[(0 * 64 + w * 8) * 64]);
        GLDS(gB + (size_t)64 * K,     &Bs[(1 * 64 + w * 8) * 64]);
        gA += 64; gB += 64;
        __syncthreads();
        #pragma unroll
        for (int kk = 0; kk < 2; ++kk) {
            const int fo = (kk * 32 + kgu * 8) ^ ((ra & 7) << 3);
            s16x8 av[2], bvv[4];
            #pragma unroll
            for (int i = 0; i < 2; ++i)
                av[i] = *(const s16x8*)&As[(wr * 32 + i * 16 + ra) * 64 + fo];
            #pragma unroll
            for (int j = 0; j < 4; ++j)
                bvv[j] = *(const s16x8*)&Bs[(wc * 64 + j * 16 + ra) * 64 + fo];
            #pragma unroll
            for (int i = 0; i < 2; ++i)
                #pragma unroll
                for (int j = 0; j < 4; ++j)
                    asm("v_mfma_f32_16x16x32_f16 %0, %1, %2, %0"
                        : "+v"(acc[i][j]) : "v"(av[i]), "v"(bvv[j]));
        }
    }

    const int cr4 = kgu * 4, cc = ra;
    #pragma unroll
    for (int j = 0; j < 4; ++j) {
        const int col = n0 + wc * 64 + j * 16 + cc;
        const float bj = bias[col];
        #pragma unroll
        for (int i = 0; i < 2; ++i) {
            const int row = m0 + wr * 32 + i * 16 + cr4;
            #pragma unroll
            for (int r = 0; r < 4; ++r)
                Cc[(size_t)(row + r) * Nn + col] = acc[i][j][r] + bj;
        }
    }
}

// ---------------- kv partials + column sums (fused), f16 in ----------------
__global__ __launch_bounds__(256)
void kv_partial(const u16* __restrict__ Kb, const u16* __restrict__ Vb,
                const float* __restrict__ sin_t, const float* __restrict__ cos_t,
                float* __restrict__ pkv, float* __restrict__ pk, float* __restrict__ pv) {
    int bh = blockIdx.x, chunk = blockIdx.y;
    int b = bh / NH, h = bh % NH;
    int t = threadIdx.x, tx = t & 15, ty = t >> 4;
    __shared__ float Kt[32][64];
    __shared__ float Vt[32][64];
    float acc[4][4] = {};
    float sk[8] = {}, sv[8] = {};
    int n0 = chunk * 128;
    int lr = t >> 3, lc = (t & 7) * 8;
    for (int nc = 0; nc < 128; nc += 32) {
        int n = n0 + nc + lr;
        size_t off = ((size_t)b * N_SEQ + n) * C_DIM + h * HD + lc;
        size_t toff = (size_t)n * HD + lc;
        u16x8 k8 = *(const u16x8*)&Kb[off];
        u16x8 v8 = *(const u16x8*)&Vb[off];
        float kf[8], vf[8];
        #pragma unroll
        for (int i = 0; i < 8; ++i) {
            kf[i] = h2f(k8[i]); vf[i] = h2f(v8[i]);
            sk[i] += kf[i]; sv[i] += vf[i];
        }
        float4 s1 = *(const float4*)&sin_t[toff];
        float4 s2 = *(const float4*)&sin_t[toff + 4];
        float4 c1 = *(const float4*)&cos_t[toff];
        float4 c2 = *(const float4*)&cos_t[toff + 4];
        float sn[8] = {s1.x, s1.y, s1.z, s1.w, s2.x, s2.y, s2.z, s2.w};
        float cs[8] = {c1.x, c1.y, c1.z, c1.w, c2.x, c2.y, c2.z, c2.w};
        float kr[8];
        #pragma unroll
        for (int e = 0; e < 8; e += 2) {
            kr[e]   = kf[e] * cs[e]     - kf[e+1] * sn[e];
            kr[e+1] = kf[e+1] * cs[e+1] + kf[e]   * sn[e+1];
        }
        __syncthreads();
        #pragma unroll
        for (int i = 0; i < 8; ++i) { Kt[lr][lc + i] = kr[i]; Vt[lr][lc + i] = vf[i]; }
        __syncthreads();
        #pragma unroll
        for (int nn = 0; nn < 32; ++nn) {
            float a[4], bb[4];
            #pragma unroll
            for (int i = 0; i < 4; ++i) a[i] = Kt[nn][ty * 4 + i];
            #pragma unroll
            for (int j = 0; j < 4; ++j) bb[j] = Vt[nn][tx * 4 + j];
            #pragma unroll
            for (int i = 0; i < 4; ++i)
                #pragma unroll
                for (int j = 0; j < 4; ++j)
                    acc[i][j] += a[i] * bb[j];
        }
    }
    size_t obase = ((size_t)bh * 32 + chunk) * 4096;
    #pragma unroll
    for (int i = 0; i < 4; ++i)
        #pragma unroll
        for (int j = 0; j < 4; ++j)
            pkv[obase + (ty * 4 + i) * 64 + (tx * 4 + j)] = acc[i][j];
    __syncthreads();
    #pragma unroll
    for (int i = 0; i < 8; ++i) { Kt[lr][lc + i] = sk[i]; Vt[lr][lc + i] = sv[i]; }
    __syncthreads();
    if (t < 64) {
        float s1 = 0.f, s2 = 0.f;
        #pragma unroll
        for (int r = 0; r < 32; ++r) { s1 += Kt[r][t]; s2 += Vt[r][t]; }
        pk[((size_t)bh * 32 + chunk) * 64 + t] = s1;
        pv[((size_t)bh * 32 + chunk) * 64 + t] = s2;
    }
}

// ---------------- merged reduce: kvT (f16 hi/lo, transposed [e][d]) + km/vm ----------------
__global__ __launch_bounds__(256)
void kvred(const float* __restrict__ pkv, const float* __restrict__ pk, const float* __restrict__ pv,
           u16* __restrict__ kvT, float* __restrict__ km, float* __restrict__ vm) {
    int bh = blockIdx.x, t = threadIdx.x;
    int u = blockIdx.y * 256 + t;
    float s = 0.f;
    for (int c = 0; c < 32; ++c) s += pkv[((size_t)bh * 32 + c) * 4096 + u];
    s *= (SCALE / N_SEQ);
    int d = u >> 6, e = u & 63;
    u16 hi = f2h(s);
    u16 lo = f2h(s - h2f(hi));
    kvT[(size_t)bh * 8192 + e * 64 + d] = hi;
    kvT[(size_t)bh * 8192 + 4096 + e * 64 + d] = lo;
    if (blockIdx.y == 0 && t < 128) {
        int which = t >> 6, lane = t & 63;
        const float* src = which ? pv : pk;
        float s2 = 0.f;
        for (int c = 0; c < 32; ++c) s2 += src[((size_t)bh * 32 + c) * 64 + lane];
        (which ? vm : km)[bh * 64 + lane] = s2 * (1.0f / N_SEQ);
    }
}

// ---------------- res: MFMA(qr @ kv_hi + qr @ kv_lo) + rescale; in-place on Qr ----------------
#define LDQ 72
__global__ __launch_bounds__(256)
void res_mfma(u16* __restrict__ Qr,
              const u16* __restrict__ kvT,
              const float* __restrict__ vmean, const float* __restrict__ zbuf) {
    __shared__ __align__(16) u16 qs[128 * LDQ];
    __shared__ __align__(16) u16 kvs[2][64 * LDQ];
    __shared__ float zs[128];
    __shared__ float vms[64];
    const int bh = blockIdx.x;
    const int b = bh / NH, h = bh % NH;
    const int n0 = blockIdx.y * 128;
    const int t = threadIdx.x;
    const int lane = t & 63, w = t >> 6;

    {   // stage kv^T hi/lo
        const int r = t >> 2, c = (t & 3) * 16;
        #pragma unroll
        for (int p = 0; p < 2; ++p) {
            size_t g = (size_t)bh * 8192 + p * 4096 + r * 64 + c;
            *(u16x8*)&kvs[p][r * LDQ + c]     = *(const u16x8*)&kvT[g];
            *(u16x8*)&kvs[p][r * LDQ + c + 8] = *(const u16x8*)&kvT[g + 8];
        }
    }
    if (t < 64) vms[t] = vmean[bh * 64 + t];
    else if (t < 192) zs[t - 64] = zbuf[(size_t)bh * N_SEQ + n0 + (t - 64)];
    // stage qr
    #pragma unroll
    for (int ri = 0; ri < 4; ++ri) {
        const int row = ri * 32 + (t >> 3);
        const int c = (t & 7) * 8;
        size_t off = ((size_t)b * N_SEQ + n0 + row) * C_DIM + (size_t)h * HD + c;
        *(u16x8*)&qs[row * LDQ + c] = *(const u16x8*)&Qr[off];
    }
    __syncthreads();

    f32x4 acc[2][4] = {};
    const int ra = lane & 15, kg = (lane >> 4) * 8;
    #pragma unroll
    for (int p = 0; p < 2; ++p) {
        #pragma unroll
        for (int hh = 0; hh < 2; ++hh) {
            s16x8 bv4[4];
            #pragma unroll
            for (int j = 0; j < 4; ++j)
                bv4[j] = *(const s16x8*)&kvs[p][(j * 16 + ra) * LDQ + hh * 32 + kg];
            #pragma unroll
            for (int i = 0; i < 2; ++i) {
                s16x8 av = *(const s16x8*)&qs[(w * 32 + i * 16 + ra) * LDQ + hh * 32 + kg];
                #pragma unroll
                for (int j = 0; j < 4; ++j)
                    asm("v_mfma_f32_16x16x32_f16 %0, %1, %2, %0"
                        : "+v"(acc[i][j]) : "v"(av), "v"(bv4[j]));
            }
        }
    }

    const int cr4 = (lane >> 4) * 4, cc = lane & 15;
    #pragma unroll
    for (int i = 0; i < 2; ++i) {
        #pragma unroll
        for (int j = 0; j < 4; ++j) {
            const int col = j * 16 + cc;
            const float vmc = vms[col];
            #pragma unroll
            for (int r = 0; r < 4; ++r) {
                const int row = w * 32 + i * 16 + cr4 + r;
                const float z = zs[row];
                const float v = acc[i][j][r] * (1.0f + 1.0f / (z + 1e-6f)) - z * vmc;
                Qr[((size_t)b * N_SEQ + n0 + row) * C_DIM + (size_t)h * HD + col] = f2h(v);
            }
        }
    }
}

extern "C" void kernel_launch(void* const* d_in, const int* in_sizes, int n_in,
                              void* d_out, int out_size, void* d_ws, size_t ws_size,
                              hipStream_t stream) {
    const float* query = (const float*)d_in[0];
    const float* key   = (const float*)d_in[1];
    const float* value = (const float*)d_in[2];
    const float* Wq = (const float*)d_in[3];
    const float* bq = (const float*)d_in[4];
    const float* Wk = (const float*)d_in[5];
    const float* bk = (const float*)d_in[6];
    const float* Wv = (const float*)d_in[7];
    const float* bv = (const float*)d_in[8];
    const float* Wo = (const float*)d_in[9];
    const float* bo = (const float*)d_in[10];
    const int* dH = (const int*)d_in[11];
    const int* dW = (const int*)d_in[12];
    float* out = (float*)d_out;

    const size_t mc = (size_t)M_ROWS * C_DIM;   // 12,582,912
    const size_t wsz = (size_t)C_DIM * C_DIM;   // 589,824

    // f16 buffers
    u16* ws16 = (u16*)d_ws;
    u16* Qr  = ws16;             // mc (qr, then res in-place)
    u16* Kb  = Qr + mc;          // mc
    u16* Vb  = Kb + mc;          // mc
    u16* wqb = Vb + mc;          // wsz x4
    u16* wkb = wqb + wsz;
    u16* wvb = wkb + wsz;
    u16* wob = wvb + wsz;
    u16* kvT = wob + wsz;        // NBH*8192 (hi/lo)

    // fp32 buffers
    float* wsf = (float*)(kvT + (size_t)NBH * 8192);
    float* sin_t = wsf;                          // 262144
    float* cos_t = sin_t + (size_t)N_SEQ * HD;   // 262144
    float* pk    = cos_t + (size_t)N_SEQ * HD;   // NBH*32*64
    float* pv    = pk + (size_t)NBH * 32 * 64;
    float* km    = pv + (size_t)NBH * 32 * 64;   // NBH*64
    float* vm    = km + NBH * 64;
    float* zbuf  = vm + NBH * 64;                // NBH*4096
    float* pkv   = zbuf + (size_t)NBH * N_SEQ;   // NBH*32*4096 = 25MB

    // merged weights-cvt + rope tables (disjoint bid ranges)
    prep<<<dim3(288 + 1024), dim3(256), 0, stream>>>(Wq, Wk, Wv, Wo,
                                                     wqb, wkb, wvb, wob,
                                                     dW, sin_t, cos_t);

    // K + V projections in ONE 1536-block launch (disjoint halves)
    gemm_kv<<<dim3(1536), dim3(512), 0, stream>>>(key, value, wkb, wvb, bk, bv, Kb, Vb);

    // kv partials (+ fused column sums), then merged reduce -> km, vm, kvT
    kv_partial<<<dim3(NBH, 32), dim3(256), 0, stream>>>(Kb, Vb, sin_t, cos_t, pkv, pk, pv);
    kvred<<<dim3(NBH, 16), dim3(256), 0, stream>>>(pkv, pk, pv, kvT, km, vm);

    // Q projection with fused exact-z + rope
    gemm_q<<<dim3(768), dim3(512), 0, stream>>>(query, wqb, bq, km, sin_t, cos_t, Qr, zbuf);

    // res (in-place on Qr)
    res_mfma<<<dim3(NBH, N_SEQ / 128), dim3(256), 0, stream>>>(Qr, kvT, vm, zbuf);

    // output projection (fp32 out)
    gemm_f16a<<<dim3(768), dim3(512), 0, stream>>>(Qr, wob, bo, out);
}